// Round 5
// baseline (1637.935 us; speedup 1.0000x reference)
//
#include <hip/hip_runtime.h>
#include <stdint.h>

// ---------------------------------------------------------------------------
// LSTM pointer-generator decoder step, B=128 TK=400 NK=50 H=E=256 V=50000.
// Round 5: OUTPUT DTYPE = FLOAT32. R2/R3/R4 produced bit-identical absmax
// because the harness reads d_out as f32 while I wrote bf16 u16s — my h/c
// bf16 pairs reinterpreted as f32 landed inside the final_dist chunk
// (u16 idx 6.4M..6.72M == f32 idx 3.2M..3.36M), giving the invariant
// -3.28125-style values. The "(bf16)" in the fail label is hardcoded; the
// threshold 0.02*3.984375 comes from bf16-quantized *expected* tensors.
// Inputs f32 (confirmed R1->R2), outputs f32, fp32 math. Intermediates in
// module __device__ globals (no d_ws assumptions).
// ---------------------------------------------------------------------------

typedef unsigned short u16;
typedef unsigned int   u32;

#define Bv  128
#define TKv 400
#define NKv 50
#define Hv  256
#define Vv  50000

// ---- module-global workspace (no d_ws dependency) -------------------------
__device__ float g_x[32768];      // x = cat @ Wx + bx
__device__ float g_h[32768];      // h_new
__device__ float g_c[32768];      // c_new
__device__ float g_sd[32768];     // s_hat@Wsd + bd
__device__ float g_sf[32768];     // s_hat@Wsf + bf
__device__ float g_e[51200];      // doc scores
__device__ float g_en[6400];      // node scores
__device__ float g_a[51200];      // doc attention a
__device__ float g_cd[32768];     // c_d
__device__ float g_cg[32768];     // c_g
__device__ float g_cg2[32768];    // c_g2
__device__ float g_pg[128];       // p_gen
__device__ float g_o1[32768];     // out1
__device__ float g_logits[6400000]; // f32 logits (25.6 MB)

__device__ __forceinline__ float sigm(float x) { return 1.f / (1.f + expf(-x)); }

// ---------------------------------------------------------------------------
// K1: embedding gather, x = [c_t_d|c_t_g|c_t_g2|emb] @ Wx + bx, LSTM cell,
//     sd = s_hat@Wsd + bd, sf = s_hat@Wsf + bf.  One block per batch row.
// ---------------------------------------------------------------------------
__global__ __launch_bounds__(256) void k_pre(
    const int* __restrict__ y,
    const float* __restrict__ h_prev, const float* __restrict__ c_prev,
    const float* __restrict__ ctd, const float* __restrict__ ctg, const float* __restrict__ ctg2,
    const float* __restrict__ emb,
    const float* __restrict__ Wx, const float* __restrict__ bx,
    const float* __restrict__ Wi, const float* __restrict__ Wh,
    const float* __restrict__ bi, const float* __restrict__ bh,
    const float* __restrict__ Wsd, const float* __restrict__ bd,
    const float* __restrict__ Wsf, const float* __restrict__ bfv,
    float* __restrict__ out_h, float* __restrict__ out_c)
{
    const int b = blockIdx.x, j = threadIdx.x;
    __shared__ float xcat[1024];
    __shared__ float xs[256], hs[256], shs[512];

    xcat[j]       = ctd[b * 256 + j];
    xcat[256 + j] = ctg[b * 256 + j];
    xcat[512 + j] = ctg2[b * 256 + j];
    xcat[768 + j] = emb[(size_t)y[b] * 256 + j];
    hs[j] = h_prev[b * 256 + j];
    __syncthreads();

    // x = xcat @ Wx[1024,256] + bx
    float acc = bx[j];
    {
        const float* wcol = Wx + j;
        #pragma unroll 4
        for (int k = 0; k < 1024; k++) acc += xcat[k] * wcol[(size_t)k * 256];
    }
    xs[j] = acc;
    g_x[b * 256 + j] = acc;
    __syncthreads();

    // gates = x@Wi + h_prev@Wh + bi + bh   (i,f,g,o chunks of 256)
    float g[4];
    #pragma unroll
    for (int gi = 0; gi < 4; gi++) {
        const int col = gi * 256 + j;
        float a2 = bi[col] + bh[col];
        const float* wic = Wi + col;
        const float* whc = Wh + col;
        #pragma unroll 4
        for (int k = 0; k < 256; k++)
            a2 += xs[k] * wic[k * 1024] + hs[k] * whc[k * 1024];
        g[gi] = a2;
    }
    float cp = c_prev[b * 256 + j];
    float cn = sigm(g[1]) * cp + sigm(g[0]) * tanhf(g[2]);
    float hn = sigm(g[3]) * tanhf(cn);
    g_h[b * 256 + j] = hn;
    g_c[b * 256 + j] = cn;
    out_h[b * 256 + j] = hn;
    out_c[b * 256 + j] = cn;
    shs[j] = hn;
    shs[256 + j] = cn;
    __syncthreads();

    // sd = s_hat@Wsd + bd ; sf = s_hat@Wsf + bf
    float asd = bd[j], asf = bfv[j];
    const float* wsdc = Wsd + j;
    const float* wsfc = Wsf + j;
    #pragma unroll 4
    for (int k = 0; k < 512; k++) {
        float sv = shs[k];
        asd += sv * wsdc[k * 256];
        asf += sv * wsfc[k * 256];
    }
    g_sd[b * 256 + j] = asd;
    g_sf[b * 256 + j] = asf;
}

// ---------------------------------------------------------------------------
// 8x8 register micro-tile GEMM step over a 32-wide K chunk.
// ---------------------------------------------------------------------------
__device__ __forceinline__ void micro_step(
    const float (*__restrict__ wsh)[256], const float (*__restrict__ es)[32],
    float acc[8][8], int tg, int jg)
{
    #pragma unroll
    for (int kk = 0; kk < 32; kk += 4) {
        float wk[4][8];
        #pragma unroll
        for (int c = 0; c < 4; c++) {
            float4 a_ = *(const float4*)&wsh[kk + c][jg * 8];
            float4 b_ = *(const float4*)&wsh[kk + c][jg * 8 + 4];
            wk[c][0] = a_.x; wk[c][1] = a_.y; wk[c][2] = a_.z; wk[c][3] = a_.w;
            wk[c][4] = b_.x; wk[c][5] = b_.y; wk[c][6] = b_.z; wk[c][7] = b_.w;
        }
        #pragma unroll
        for (int tt = 0; tt < 8; tt++) {
            float4 ev = *(const float4*)&es[tg * 8 + tt][kk];
            #pragma unroll
            for (int jj = 0; jj < 8; jj++)
                acc[tt][jj] += ev.x * wk[0][jj] + ev.y * wk[1][jj]
                             + ev.z * wk[2][jj] + ev.w * wk[3][jj];
        }
    }
}

// ---------------------------------------------------------------------------
// K2/K4: e[b,t] = vv . tanh( src[b,t,:]@W + addv[b,:] + cov[b,t]*wcw )
// grid = (ceil(R/64), B), block = 256.
// ---------------------------------------------------------------------------
__global__ __launch_bounds__(256) void k_scores(
    const float* __restrict__ src, int R,
    const float* __restrict__ W,
    const float* __restrict__ addv,
    const float* __restrict__ cov,   // nullptr for node attention
    const float* __restrict__ wcw,   // nullptr for node attention
    const float* __restrict__ vv,
    float* __restrict__ eout)
{
    __shared__ float wsh[32][256];
    __shared__ float es[64][32];
    const int b = blockIdx.y;
    const int t0 = blockIdx.x * 64;
    const int tid = threadIdx.x;
    const int jg = tid & 31;
    const int tg = tid >> 5;

    float acc[8][8];
    #pragma unroll
    for (int i = 0; i < 8; i++)
        #pragma unroll
        for (int jj = 0; jj < 8; jj++) acc[i][jj] = 0.f;

    const float* srcb = src + (size_t)b * R * 256;

    for (int k0 = 0; k0 < 256; k0 += 32) {
        #pragma unroll
        for (int i = 0; i < 8; i++) {
            int e0 = i * 1024 + tid * 4;
            int kk = e0 >> 8, cc = e0 & 255;
            *(float4*)&wsh[kk][cc] = *(const float4*)(W + (k0 + kk) * 256 + cc);
        }
        #pragma unroll
        for (int i = 0; i < 2; i++) {
            int e0 = i * 1024 + tid * 4;
            int row = e0 >> 5, kk = e0 & 31;
            int t = t0 + row;
            float4 t4 = {0.f, 0.f, 0.f, 0.f};
            if (t < R) t4 = *(const float4*)(srcb + (size_t)t * 256 + k0 + kk);
            *(float4*)&es[row][kk] = t4;
        }
        __syncthreads();
        micro_step(wsh, es, acc, tg, jg);
        __syncthreads();
    }

    const int jb = jg * 8;
    float addj[8], vvj[8], wcj[8];
    #pragma unroll
    for (int jj = 0; jj < 8; jj++) {
        addj[jj] = addv[b * 256 + jb + jj];
        vvj[jj]  = vv[jb + jj];
        wcj[jj]  = wcw ? wcw[jb + jj] : 0.f;
    }
    #pragma unroll
    for (int tt = 0; tt < 8; tt++) {
        int t = t0 + tg * 8 + tt;
        float covt = 0.f;
        if (cov && t < R) covt = cov[b * R + t];
        float s = 0.f;
        #pragma unroll
        for (int jj = 0; jj < 8; jj++) {
            float val = acc[tt][jj] + addj[jj] + covt * wcj[jj];
            s += vvj[jj] * tanhf(val);
        }
        #pragma unroll
        for (int off = 1; off < 32; off <<= 1) s += __shfl_xor(s, off, 64);
        if (jg == 0 && t < R) eout[b * R + t] = s;
    }
}

// ---------------------------------------------------------------------------
// K3: doc softmax (+mask renorm), a, coverage_next, c_d, flow_next.
// ---------------------------------------------------------------------------
__global__ __launch_bounds__(256) void k_doc(
    const float* __restrict__ enc,
    const float* __restrict__ mask,
    const float* __restrict__ cov,
    const float* __restrict__ n2t,
    float* __restrict__ out_a, float* __restrict__ out_cov,
    float* __restrict__ out_cd, float* __restrict__ out_flow)
{
    const int b = blockIdx.x, tid = threadIdx.x;
    __shared__ float as_[TKv];
    __shared__ float red[256];
    __shared__ float fl[NKv];

    float m = -1e30f;
    for (int t = tid; t < TKv; t += 256) m = fmaxf(m, g_e[b * TKv + t]);
    red[tid] = m; __syncthreads();
    for (int s = 128; s > 0; s >>= 1) { if (tid < s) red[tid] = fmaxf(red[tid], red[tid + s]); __syncthreads(); }
    m = red[0]; __syncthreads();

    float ls = 0.f;
    for (int t = tid; t < TKv; t += 256) {
        float p = expf(g_e[b * TKv + t] - m) * mask[b * TKv + t];
        as_[t] = p; ls += p;
    }
    red[tid] = ls; __syncthreads();
    for (int s = 128; s > 0; s >>= 1) { if (tid < s) red[tid] += red[tid + s]; __syncthreads(); }
    float inv = 1.f / red[0]; __syncthreads();

    for (int t = tid; t < TKv; t += 256) {
        float a = as_[t] * inv;
        as_[t] = a;
        g_a[b * TKv + t] = a;
        out_a[b * TKv + t] = a;
        out_cov[b * TKv + t] = cov[b * TKv + t] + a;
    }
    __syncthreads();

    // c_d = sum_t a[t] * enc[b,t,:]
    float cd = 0.f;
    const float* eb = enc + (size_t)b * TKv * 256 + tid;
    #pragma unroll 4
    for (int t = 0; t < TKv; t++) cd += as_[t] * eb[(size_t)t * 256];
    g_cd[b * 256 + tid] = cd;
    out_cd[b * 256 + tid] = cd;

    // flow_[n] = max_t a[t]*n2t[b,n,t]; flow_next = flow_/sum
    if (tid < NKv) {
        const float* nb = n2t + ((size_t)b * NKv + tid) * TKv;
        float mx = 0.f;
        for (int t = 0; t < TKv; t++) mx = fmaxf(mx, as_[t] * nb[t]);
        fl[tid] = mx;
    }
    __syncthreads();
    float fv = (tid < NKv) ? fl[tid] : 0.f;
    red[tid] = fv; __syncthreads();
    for (int s = 128; s > 0; s >>= 1) { if (tid < s) red[tid] += red[tid + s]; __syncthreads(); }
    float fs = red[0];
    if (tid < NKv) out_flow[b * NKv + tid] = fl[tid] / fs;
}

// ---------------------------------------------------------------------------
// K5: node softmax chain (an, c_g, an2, c_g2, a_n2t), p_gen, out1.
// ---------------------------------------------------------------------------
__global__ __launch_bounds__(256) void k_node(
    const float* __restrict__ encn,
    const float* __restrict__ maskn,
    const float* __restrict__ flow,
    const float* __restrict__ graph,
    const float* __restrict__ n2t,
    const float* __restrict__ Wpg, const float* __restrict__ bpg,
    const float* __restrict__ W1, const float* __restrict__ b1,
    float* __restrict__ out_cg, float* __restrict__ out_cg2,
    float* __restrict__ out_ant, float* __restrict__ out_pgen)
{
    const int b = blockIdx.x, tid = threadIdx.x;
    __shared__ float ans[NKv], an2s[NKv], red[256], cat[1024];

    float v = (tid < NKv) ? g_en[b * NKv + tid] : -1e30f;
    red[tid] = v; __syncthreads();
    for (int s = 128; s > 0; s >>= 1) { if (tid < s) red[tid] = fmaxf(red[tid], red[tid + s]); __syncthreads(); }
    float m = red[0]; __syncthreads();

    float p = (tid < NKv) ? expf(v - m) * maskn[b * NKv + tid] : 0.f;
    red[tid] = p; __syncthreads();
    for (int s = 128; s > 0; s >>= 1) { if (tid < s) red[tid] += red[tid + s]; __syncthreads(); }
    float S = red[0]; __syncthreads();
    p = (tid < NKv) ? (p / S) * flow[b * NKv + tid] : 0.f;
    red[tid] = p; __syncthreads();
    for (int s = 128; s > 0; s >>= 1) { if (tid < s) red[tid] += red[tid + s]; __syncthreads(); }
    float S2 = red[0]; __syncthreads();
    if (tid < NKv) ans[tid] = p / S2;
    __syncthreads();

    // c_g
    float cg = 0.f;
    const float* enb = encn + (size_t)b * NKv * 256 + tid;
    #pragma unroll
    for (int n = 0; n < NKv; n++) cg += ans[n] * enb[n * 256];
    g_cg[b * 256 + tid] = cg;
    out_cg[b * 256 + tid] = cg;

    // an2 = (an @ graph) * mask, renorm
    float q = 0.f;
    if (tid < NKv) {
        const float* gb = graph + (size_t)b * NKv * NKv + tid;
        #pragma unroll
        for (int n = 0; n < NKv; n++) q += ans[n] * gb[n * NKv];
        q *= maskn[b * NKv + tid];
    }
    red[tid] = q; __syncthreads();
    for (int s = 128; s > 0; s >>= 1) { if (tid < s) red[tid] += red[tid + s]; __syncthreads(); }
    float S3 = red[0]; __syncthreads();
    if (tid < NKv) an2s[tid] = q / S3;
    __syncthreads();

    // c_g2
    float cg2 = 0.f;
    #pragma unroll
    for (int n = 0; n < NKv; n++) cg2 += an2s[n] * enb[n * 256];
    g_cg2[b * 256 + tid] = cg2;
    out_cg2[b * 256 + tid] = cg2;

    // a_n2t = an @ n2t, renorm over t
    float at0 = 0.f, at1 = 0.f;
    {
        const float* nb = n2t + (size_t)b * NKv * TKv;
        #pragma unroll
        for (int n = 0; n < NKv; n++) {
            float an = ans[n];
            at0 += an * nb[n * TKv + tid];
            if (tid + 256 < TKv) at1 += an * nb[n * TKv + tid + 256];
        }
    }
    float loc = at0 + ((tid + 256 < TKv) ? at1 : 0.f);
    red[tid] = loc; __syncthreads();
    for (int s = 128; s > 0; s >>= 1) { if (tid < s) red[tid] += red[tid + s]; __syncthreads(); }
    float S4 = red[0]; __syncthreads();
    out_ant[b * TKv + tid] = at0 / S4;
    if (tid + 256 < TKv) out_ant[b * TKv + tid + 256] = at1 / S4;

    // p_gen = sigmoid([c_d, c_g, c_g2, h, c, x] . Wpg + bpg)
    float hvv = g_h[b * 256 + tid], cvv = g_c[b * 256 + tid];
    float xvv = g_x[b * 256 + tid], cdv = g_cd[b * 256 + tid];
    float part = cdv * Wpg[tid]        + cg  * Wpg[256 + tid]
               + cg2 * Wpg[512 + tid]  + hvv * Wpg[768 + tid]
               + cvv * Wpg[1024 + tid] + xvv * Wpg[1280 + tid];
    red[tid] = part; __syncthreads();
    for (int s = 128; s > 0; s >>= 1) { if (tid < s) red[tid] += red[tid + s]; __syncthreads(); }
    float pg = sigm(red[0] + bpg[0]);
    __syncthreads();
    if (tid == 0) { g_pg[b] = pg; out_pgen[b] = pg; }

    // out1 = [h, c_d, c_g, c_g2] @ W1 + b1
    cat[tid] = hvv; cat[256 + tid] = cdv; cat[512 + tid] = cg; cat[768 + tid] = cg2;
    __syncthreads();
    float o = b1[tid];
    const float* w1c = W1 + tid;
    #pragma unroll 4
    for (int k = 0; k < 1024; k++) o += cat[k] * w1c[k * 256];
    g_o1[b * 256 + tid] = o;
}

// ---------------------------------------------------------------------------
// K7: logits = out1[128,256] @ W2[256,50000] + b2 -> g_logits (f32).
// grid = (196, 2), 64x256 tiles.
// ---------------------------------------------------------------------------
__global__ __launch_bounds__(256) void k_logits(
    const float* __restrict__ W2,
    const float* __restrict__ b2)
{
    __shared__ float wsh[32][256];
    __shared__ float as_[64][32];
    const int m0 = blockIdx.y * 64;
    const int v0 = blockIdx.x * 256;
    const int tid = threadIdx.x;
    const int jg = tid & 31, tg = tid >> 5;

    float acc[8][8];
    #pragma unroll
    for (int i = 0; i < 8; i++)
        #pragma unroll
        for (int jj = 0; jj < 8; jj++) acc[i][jj] = 0.f;

    for (int k0 = 0; k0 < 256; k0 += 32) {
        #pragma unroll
        for (int i = 0; i < 8; i++) {
            int e0 = i * 1024 + tid * 4;
            int kk = e0 >> 8, cc = e0 & 255;
            int v = v0 + cc;
            float4 t4 = {0.f, 0.f, 0.f, 0.f};
            const float* wr = W2 + (size_t)(k0 + kk) * Vv;
            if (v + 3 < Vv) {
                t4 = *(const float4*)(wr + v);
            } else {
                if (v     < Vv) t4.x = wr[v];
                if (v + 1 < Vv) t4.y = wr[v + 1];
                if (v + 2 < Vv) t4.z = wr[v + 2];
                if (v + 3 < Vv) t4.w = wr[v + 3];
            }
            *(float4*)&wsh[kk][cc] = t4;
        }
        #pragma unroll
        for (int i = 0; i < 2; i++) {
            int e0 = i * 1024 + tid * 4;
            int row = e0 >> 5, kk = e0 & 31;
            float4 t4 = *(const float4*)(g_o1 + (m0 + row) * 256 + k0 + kk);
            *(float4*)&as_[row][kk] = t4;
        }
        __syncthreads();
        micro_step(wsh, as_, acc, tg, jg);
        __syncthreads();
    }

    #pragma unroll
    for (int tt = 0; tt < 8; tt++) {
        int mrow = m0 + tg * 8 + tt;
        #pragma unroll
        for (int jj = 0; jj < 8; jj++) {
            int v = v0 + jg * 8 + jj;
            if (v < Vv) g_logits[(size_t)mrow * Vv + v] = acc[tt][jj] + b2[v];
        }
    }
}

// ---------------------------------------------------------------------------
// K8: fused per-row softmax over V (f32 g_logits -> f32 out, scaled by
// p_gen) + row-local pointer scatter (1-pg)*a[b,t] at voc_d[b,t].
// One block per batch row; scatter after an in-block fence+barrier.
// ---------------------------------------------------------------------------
__global__ __launch_bounds__(256) void k_vsoft(
    float* __restrict__ outF, const int* __restrict__ vocd)
{
    const int b = blockIdx.x, tid = threadIdx.x;
    __shared__ float rm[256], rs[256];
    const float* Lb = g_logits + (size_t)b * Vv;
    float* Ob = outF + (size_t)b * Vv;

    float m = -1e30f, s = 0.f;
    for (int v = tid; v < Vv; v += 256) {
        float x = Lb[v];
        if (x > m) { s = s * expf(m - x) + 1.f; m = x; }
        else       { s += expf(x - m); }
    }
    rm[tid] = m; rs[tid] = s; __syncthreads();
    for (int off = 128; off > 0; off >>= 1) {
        if (tid < off) {
            float m1 = rm[tid], m2 = rm[tid + off], s1 = rs[tid], s2 = rs[tid + off];
            float M = fmaxf(m1, m2);
            rs[tid] = s1 * expf(m1 - M) + s2 * expf(m2 - M);
            rm[tid] = M;
        }
        __syncthreads();
    }
    const float M = rm[0];
    const float pg = g_pg[b];
    const float inv = pg / rs[0];
    for (int v = tid; v < Vv; v += 256) Ob[v] = expf(Lb[v] - M) * inv;

    __threadfence();
    __syncthreads();

    // row-local scatter: add (1-pg)*a[b,t] at voc_d[b,t] (dup indices ok)
    const float omp = 1.f - pg;
    for (int t = tid; t < TKv; t += 256)
        atomicAdd(Ob + vocd[b * TKv + t], omp * g_a[b * TKv + t]);
}

// ---------------------------------------------------------------------------

extern "C" void kernel_launch(void* const* d_in, const int* in_sizes, int n_in,
                              void* d_out, int out_size, void* d_ws, size_t ws_size,
                              hipStream_t stream)
{
    (void)in_sizes; (void)n_in; (void)out_size; (void)d_ws; (void)ws_size;

    const int*   y      = (const int*)d_in[0];
    const float* h_prev = (const float*)d_in[1];
    const float* c_prev = (const float*)d_in[2];
    const float* enc    = (const float*)d_in[3];
    const float* encn   = (const float*)d_in[4];
    const float* mask   = (const float*)d_in[5];
    const float* maskn  = (const float*)d_in[6];
    const float* ctd    = (const float*)d_in[7];
    const float* ctg    = (const float*)d_in[8];
    const float* ctg2   = (const float*)d_in[9];
    const float* cov    = (const float*)d_in[10];
    const float* flow   = (const float*)d_in[11];
    const float* n2t    = (const float*)d_in[12];
    const float* graph  = (const float*)d_in[13];
    const int*   vocd   = (const int*)d_in[14];
    // d_in[15] = step (unused)
    const float* emb    = (const float*)d_in[16];
    const float* Wx     = (const float*)d_in[17];
    const float* bx     = (const float*)d_in[18];
    const float* Wi     = (const float*)d_in[19];
    const float* Wh     = (const float*)d_in[20];
    const float* bi     = (const float*)d_in[21];
    const float* bh     = (const float*)d_in[22];
    const float* Whd    = (const float*)d_in[23];
    const float* Wsd    = (const float*)d_in[24];
    const float* wcdw   = (const float*)d_in[25];
    const float* vd     = (const float*)d_in[26];
    const float* bd     = (const float*)d_in[27];
    const float* Wn     = (const float*)d_in[28];
    const float* Wsf    = (const float*)d_in[29];
    const float* vf     = (const float*)d_in[30];
    const float* bfv    = (const float*)d_in[31];
    const float* Wpg    = (const float*)d_in[32];
    const float* bpg    = (const float*)d_in[33];
    const float* W1     = (const float*)d_in[34];
    const float* b1     = (const float*)d_in[35];
    const float* W2     = (const float*)d_in[36];
    const float* b2     = (const float*)d_in[37];

    float* o = (float*)d_out;                 // FLOAT32 output
    float* o_final = o;                       // 6,400,000
    float* o_h     = o + 6400000;             // 32768
    float* o_c     = o + 6432768;             // 32768
    float* o_cd    = o + 6465536;             // 32768
    float* o_cg    = o + 6498304;             // 32768
    float* o_cg2   = o + 6531072;             // 32768
    float* o_a     = o + 6563840;             // 51200
    float* o_ant   = o + 6615040;             // 51200
    float* o_pg    = o + 6666240;             // 128
    float* o_cov   = o + 6666368;             // 51200
    float* o_fl    = o + 6717568;             // 6400

    float* g_e_p;  hipGetSymbolAddress((void**)&g_e_p,  HIP_SYMBOL(g_e));
    float* g_en_p; hipGetSymbolAddress((void**)&g_en_p, HIP_SYMBOL(g_en));
    float* g_sd_p; hipGetSymbolAddress((void**)&g_sd_p, HIP_SYMBOL(g_sd));
    float* g_sf_p; hipGetSymbolAddress((void**)&g_sf_p, HIP_SYMBOL(g_sf));

    k_pre<<<dim3(Bv), dim3(256), 0, stream>>>(
        y, h_prev, c_prev, ctd, ctg, ctg2, emb, Wx, bx, Wi, Wh, bi, bh,
        Wsd, bd, Wsf, bfv, o_h, o_c);

    k_scores<<<dim3(7, Bv), dim3(256), 0, stream>>>(
        enc, TKv, Whd, g_sd_p, cov, wcdw, vd, g_e_p);

    k_scores<<<dim3(1, Bv), dim3(256), 0, stream>>>(
        encn, NKv, Wn, g_sf_p, nullptr, nullptr, vf, g_en_p);

    k_doc<<<dim3(Bv), dim3(256), 0, stream>>>(
        enc, mask, cov, n2t, o_a, o_cov, o_cd, o_fl);

    k_node<<<dim3(Bv), dim3(256), 0, stream>>>(
        encn, maskn, flow, graph, n2t, Wpg, bpg, W1, b1,
        o_cg, o_cg2, o_ant, o_pg);

    k_logits<<<dim3(196, 2), dim3(256), 0, stream>>>(W2, b2);

    k_vsoft<<<dim3(Bv), dim3(256), 0, stream>>>(o_final, vocd);
}

// Round 6
// 983.972 us; speedup vs baseline: 1.6646x; 1.6646x over previous
//
#include <hip/hip_runtime.h>
#include <stdint.h>

// ---------------------------------------------------------------------------
// LSTM pointer-generator decoder step, B=128 TK=400 NK=50 H=E=256 V=50000.
// Round 6: MFMA for the two big GEMMs. R5 counters: k_scores VGPR=256 +
// 215 MB scratch writes (register spills), MfmaUtil=0, 464 us. Fix:
// bf16 16x16x32 MFMA with pre-transposed bf16 weights (k_tc kernel) so
// B-frags are contiguous 16B loads; A-frags cast f32->bf16 on the fly.
// C/D map (verified, guide m89/m91): col=lane&15, row=quad*4+reg.
// k_pre/k_doc/k_node/k_vsoft unchanged from the passing R5 version.
// ---------------------------------------------------------------------------

typedef unsigned short u16;
typedef unsigned int   u32;

#define Bv  128
#define TKv 400
#define NKv 50
#define Hv  256
#define Vv  50000
#define VPAD 50176   // 50000 padded to multiple of 128

typedef __attribute__((ext_vector_type(8))) short bf16x8;
typedef __attribute__((ext_vector_type(4))) float f32x4;

// ---- module-global workspace (no d_ws dependency) -------------------------
__device__ float g_x[32768];      // x = cat @ Wx + bx
__device__ float g_h[32768];      // h_new
__device__ float g_c[32768];      // c_new
__device__ float g_sd[32768];     // s_hat@Wsd + bd
__device__ float g_sf[32768];     // s_hat@Wsf + bf
__device__ float g_e[51200];      // doc scores
__device__ float g_en[6400];      // node scores
__device__ float g_a[51200];      // doc attention a
__device__ float g_cd[32768];     // c_d
__device__ float g_cg[32768];     // c_g
__device__ float g_cg2[32768];    // c_g2
__device__ float g_pg[128];       // p_gen
__device__ float g_o1[32768];     // out1
__device__ float g_logits[6400000];        // f32 logits (25.6 MB)
__device__ u16   g_Wdt[256 * 256];         // Whd^T bf16 [n][k]
__device__ u16   g_Wnt[256 * 256];         // Wn^T  bf16 [n][k]
__device__ u16   g_W2t[(size_t)VPAD * 256];// W2^T  bf16 [v][k] (25.7 MB)

__device__ __forceinline__ float sigm(float x) { return 1.f / (1.f + expf(-x)); }

__device__ __forceinline__ u16 f2bf(float f) {
    u32 u = __float_as_uint(f);
    return (u16)((u + 0x7fffu + ((u >> 16) & 1u)) >> 16);  // RNE
}

__device__ __forceinline__ bf16x8 cvt8(const float* __restrict__ p) {
    const float4 a = *(const float4*)p;
    const float4 b = *(const float4*)(p + 4);
    bf16x8 r;
    r[0] = (short)f2bf(a.x); r[1] = (short)f2bf(a.y);
    r[2] = (short)f2bf(a.z); r[3] = (short)f2bf(a.w);
    r[4] = (short)f2bf(b.x); r[5] = (short)f2bf(b.y);
    r[6] = (short)f2bf(b.z); r[7] = (short)f2bf(b.w);
    return r;
}

// tanh via exp; clamp so exp never overflows (tanh saturated anyway)
__device__ __forceinline__ float fast_tanh(float x) {
    x = fminf(fmaxf(x, -15.f), 15.f);
    float e = __expf(2.f * x);
    return (e - 1.f) / (e + 1.f);
}

// ---------------------------------------------------------------------------
// K0: transpose-cast  src[K][N] f32  ->  dst[n][k] bf16.
// grid = (Npad/32, K/32), block 256 (32x8). Reads n>=N give 0 (pad rows).
// ---------------------------------------------------------------------------
__global__ __launch_bounds__(256) void k_tc(
    const float* __restrict__ src, u16* __restrict__ dst, int K, int N)
{
    __shared__ float tile[32][33];
    const int n0 = blockIdx.x * 32, k0 = blockIdx.y * 32;
    const int tx = threadIdx.x & 31, ty = threadIdx.x >> 5;
    #pragma unroll
    for (int i = 0; i < 32; i += 8) {
        int k = k0 + ty + i, n = n0 + tx;
        tile[ty + i][tx] = (n < N) ? src[(size_t)k * N + n] : 0.f;
    }
    __syncthreads();
    #pragma unroll
    for (int i = 0; i < 32; i += 8) {
        int n = n0 + ty + i, k = k0 + tx;
        dst[(size_t)n * K + k] = f2bf(tile[tx][ty + i]);
    }
}

// ---------------------------------------------------------------------------
// K1: embedding gather, x = [c_t_d|c_t_g|c_t_g2|emb] @ Wx + bx, LSTM cell,
//     sd = s_hat@Wsd + bd, sf = s_hat@Wsf + bf.  One block per batch row.
// ---------------------------------------------------------------------------
__global__ __launch_bounds__(256) void k_pre(
    const int* __restrict__ y,
    const float* __restrict__ h_prev, const float* __restrict__ c_prev,
    const float* __restrict__ ctd, const float* __restrict__ ctg, const float* __restrict__ ctg2,
    const float* __restrict__ emb,
    const float* __restrict__ Wx, const float* __restrict__ bx,
    const float* __restrict__ Wi, const float* __restrict__ Wh,
    const float* __restrict__ bi, const float* __restrict__ bh,
    const float* __restrict__ Wsd, const float* __restrict__ bd,
    const float* __restrict__ Wsf, const float* __restrict__ bfv,
    float* __restrict__ out_h, float* __restrict__ out_c)
{
    const int b = blockIdx.x, j = threadIdx.x;
    __shared__ float xcat[1024];
    __shared__ float xs[256], hs[256], shs[512];

    xcat[j]       = ctd[b * 256 + j];
    xcat[256 + j] = ctg[b * 256 + j];
    xcat[512 + j] = ctg2[b * 256 + j];
    xcat[768 + j] = emb[(size_t)y[b] * 256 + j];
    hs[j] = h_prev[b * 256 + j];
    __syncthreads();

    float acc = bx[j];
    {
        const float* wcol = Wx + j;
        #pragma unroll 4
        for (int k = 0; k < 1024; k++) acc += xcat[k] * wcol[(size_t)k * 256];
    }
    xs[j] = acc;
    g_x[b * 256 + j] = acc;
    __syncthreads();

    float g[4];
    #pragma unroll
    for (int gi = 0; gi < 4; gi++) {
        const int col = gi * 256 + j;
        float a2 = bi[col] + bh[col];
        const float* wic = Wi + col;
        const float* whc = Wh + col;
        #pragma unroll 4
        for (int k = 0; k < 256; k++)
            a2 += xs[k] * wic[k * 1024] + hs[k] * whc[k * 1024];
        g[gi] = a2;
    }
    float cp = c_prev[b * 256 + j];
    float cn = sigm(g[1]) * cp + sigm(g[0]) * tanhf(g[2]);
    float hn = sigm(g[3]) * tanhf(cn);
    g_h[b * 256 + j] = hn;
    g_c[b * 256 + j] = cn;
    out_h[b * 256 + j] = hn;
    out_c[b * 256 + j] = cn;
    shs[j] = hn;
    shs[256 + j] = cn;
    __syncthreads();

    float asd = bd[j], asf = bfv[j];
    const float* wsdc = Wsd + j;
    const float* wsfc = Wsf + j;
    #pragma unroll 4
    for (int k = 0; k < 512; k++) {
        float sv = shs[k];
        asd += sv * wsdc[k * 256];
        asf += sv * wsfc[k * 256];
    }
    g_sd[b * 256 + j] = asd;
    g_sf[b * 256 + j] = asf;
}

// ---------------------------------------------------------------------------
// K2/K4 (MFMA): e[b,t] = vv . tanh( src[b,t,:]@W + addv[b,:] + cov[b,t]*wcw )
// Wt is the bf16 transposed weight [n][k]. grid (ceil(R/64), B), block 256.
// Wave w handles rows t0+w*16..+15 (one 16-row M-tile x 16 N-tiles, K=256).
// ---------------------------------------------------------------------------
__global__ __launch_bounds__(256) void k_scores(
    const float* __restrict__ src, int R,
    const u16* __restrict__ Wt,
    const float* __restrict__ addv,
    const float* __restrict__ cov,   // nullptr for node attention
    const float* __restrict__ wcw,   // nullptr for node attention
    const float* __restrict__ vv,
    float* __restrict__ eout)
{
    const int b = blockIdx.y, t0 = blockIdx.x * 64;
    const int tid = threadIdx.x;
    const int lane = tid & 63, wave = tid >> 6;
    const int nlow = lane & 15, quad = lane >> 4;
    const int trow = t0 + wave * 16 + nlow;
    const bool tval = trow < R;
    const float* arow = src + ((size_t)b * R + trow) * 256 + quad * 8;
    const u16* brow = Wt + nlow * 256 + quad * 8;

    const f32x4 zf = {0.f, 0.f, 0.f, 0.f};
    f32x4 acc[16];
    #pragma unroll
    for (int i = 0; i < 16; i++) acc[i] = zf;

    for (int k0 = 0; k0 < 256; k0 += 32) {
        bf16x8 af = {0, 0, 0, 0, 0, 0, 0, 0};
        if (tval) af = cvt8(arow + k0);
        #pragma unroll
        for (int nt = 0; nt < 16; nt++) {
            bf16x8 bf = *(const bf16x8*)(brow + nt * 4096 + k0);
            acc[nt] = __builtin_amdgcn_mfma_f32_16x16x32_bf16(af, bf, acc[nt], 0, 0, 0);
        }
    }

    // epilogue: C row = quad*4+r, col = nt*16+nlow
    float covt[4];
    #pragma unroll
    for (int r = 0; r < 4; r++) {
        int t = t0 + wave * 16 + quad * 4 + r;
        covt[r] = (cov && t < R) ? cov[b * R + t] : 0.f;
    }
    float s4[4] = {0.f, 0.f, 0.f, 0.f};
    #pragma unroll
    for (int nt = 0; nt < 16; nt++) {
        int col = nt * 16 + nlow;
        float vvc = vv[col];
        float adc = addv[b * 256 + col];
        float wcc = wcw ? wcw[col] : 0.f;
        #pragma unroll
        for (int r = 0; r < 4; r++)
            s4[r] += vvc * fast_tanh(acc[nt][r] + adc + covt[r] * wcc);
    }
    #pragma unroll
    for (int r = 0; r < 4; r++) {
        float s = s4[r];
        s += __shfl_xor(s, 1, 64);
        s += __shfl_xor(s, 2, 64);
        s += __shfl_xor(s, 4, 64);
        s += __shfl_xor(s, 8, 64);
        int t = t0 + wave * 16 + quad * 4 + r;
        if (nlow == 0 && t < R) eout[b * R + t] = s;
    }
}

// ---------------------------------------------------------------------------
// K3: doc softmax (+mask renorm), a, coverage_next, c_d, flow_next.
// ---------------------------------------------------------------------------
__global__ __launch_bounds__(256) void k_doc(
    const float* __restrict__ enc,
    const float* __restrict__ mask,
    const float* __restrict__ cov,
    const float* __restrict__ n2t,
    float* __restrict__ out_a, float* __restrict__ out_cov,
    float* __restrict__ out_cd, float* __restrict__ out_flow)
{
    const int b = blockIdx.x, tid = threadIdx.x;
    __shared__ float as_[TKv];
    __shared__ float red[256];
    __shared__ float fl[NKv];

    float m = -1e30f;
    for (int t = tid; t < TKv; t += 256) m = fmaxf(m, g_e[b * TKv + t]);
    red[tid] = m; __syncthreads();
    for (int s = 128; s > 0; s >>= 1) { if (tid < s) red[tid] = fmaxf(red[tid], red[tid + s]); __syncthreads(); }
    m = red[0]; __syncthreads();

    float ls = 0.f;
    for (int t = tid; t < TKv; t += 256) {
        float p = expf(g_e[b * TKv + t] - m) * mask[b * TKv + t];
        as_[t] = p; ls += p;
    }
    red[tid] = ls; __syncthreads();
    for (int s = 128; s > 0; s >>= 1) { if (tid < s) red[tid] += red[tid + s]; __syncthreads(); }
    float inv = 1.f / red[0]; __syncthreads();

    for (int t = tid; t < TKv; t += 256) {
        float a = as_[t] * inv;
        as_[t] = a;
        g_a[b * TKv + t] = a;
        out_a[b * TKv + t] = a;
        out_cov[b * TKv + t] = cov[b * TKv + t] + a;
    }
    __syncthreads();

    float cd = 0.f;
    const float* eb = enc + (size_t)b * TKv * 256 + tid;
    #pragma unroll 4
    for (int t = 0; t < TKv; t++) cd += as_[t] * eb[(size_t)t * 256];
    g_cd[b * 256 + tid] = cd;
    out_cd[b * 256 + tid] = cd;

    if (tid < NKv) {
        const float* nb = n2t + ((size_t)b * NKv + tid) * TKv;
        float mx = 0.f;
        for (int t = 0; t < TKv; t++) mx = fmaxf(mx, as_[t] * nb[t]);
        fl[tid] = mx;
    }
    __syncthreads();
    float fv = (tid < NKv) ? fl[tid] : 0.f;
    red[tid] = fv; __syncthreads();
    for (int s = 128; s > 0; s >>= 1) { if (tid < s) red[tid] += red[tid + s]; __syncthreads(); }
    float fs = red[0];
    if (tid < NKv) out_flow[b * NKv + tid] = fl[tid] / fs;
}

// ---------------------------------------------------------------------------
// K5: node softmax chain (an, c_g, an2, c_g2, a_n2t), p_gen, out1.
// ---------------------------------------------------------------------------
__global__ __launch_bounds__(256) void k_node(
    const float* __restrict__ encn,
    const float* __restrict__ maskn,
    const float* __restrict__ flow,
    const float* __restrict__ graph,
    const float* __restrict__ n2t,
    const float* __restrict__ Wpg, const float* __restrict__ bpg,
    const float* __restrict__ W1, const float* __restrict__ b1,
    float* __restrict__ out_cg, float* __restrict__ out_cg2,
    float* __restrict__ out_ant, float* __restrict__ out_pgen)
{
    const int b = blockIdx.x, tid = threadIdx.x;
    __shared__ float ans[NKv], an2s[NKv], red[256], cat[1024];

    float v = (tid < NKv) ? g_en[b * NKv + tid] : -1e30f;
    red[tid] = v; __syncthreads();
    for (int s = 128; s > 0; s >>= 1) { if (tid < s) red[tid] = fmaxf(red[tid], red[tid + s]); __syncthreads(); }
    float m = red[0]; __syncthreads();

    float p = (tid < NKv) ? expf(v - m) * maskn[b * NKv + tid] : 0.f;
    red[tid] = p; __syncthreads();
    for (int s = 128; s > 0; s >>= 1) { if (tid < s) red[tid] += red[tid + s]; __syncthreads(); }
    float S = red[0]; __syncthreads();
    p = (tid < NKv) ? (p / S) * flow[b * NKv + tid] : 0.f;
    red[tid] = p; __syncthreads();
    for (int s = 128; s > 0; s >>= 1) { if (tid < s) red[tid] += red[tid + s]; __syncthreads(); }
    float S2 = red[0]; __syncthreads();
    if (tid < NKv) ans[tid] = p / S2;
    __syncthreads();

    float cg = 0.f;
    const float* enb = encn + (size_t)b * NKv * 256 + tid;
    #pragma unroll
    for (int n = 0; n < NKv; n++) cg += ans[n] * enb[n * 256];
    g_cg[b * 256 + tid] = cg;
    out_cg[b * 256 + tid] = cg;

    float q = 0.f;
    if (tid < NKv) {
        const float* gb = graph + (size_t)b * NKv * NKv + tid;
        #pragma unroll
        for (int n = 0; n < NKv; n++) q += ans[n] * gb[n * NKv];
        q *= maskn[b * NKv + tid];
    }
    red[tid] = q; __syncthreads();
    for (int s = 128; s > 0; s >>= 1) { if (tid < s) red[tid] += red[tid + s]; __syncthreads(); }
    float S3 = red[0]; __syncthreads();
    if (tid < NKv) an2s[tid] = q / S3;
    __syncthreads();

    float cg2 = 0.f;
    #pragma unroll
    for (int n = 0; n < NKv; n++) cg2 += an2s[n] * enb[n * 256];
    g_cg2[b * 256 + tid] = cg2;
    out_cg2[b * 256 + tid] = cg2;

    float at0 = 0.f, at1 = 0.f;
    {
        const float* nb = n2t + (size_t)b * NKv * TKv;
        #pragma unroll
        for (int n = 0; n < NKv; n++) {
            float an = ans[n];
            at0 += an * nb[n * TKv + tid];
            if (tid + 256 < TKv) at1 += an * nb[n * TKv + tid + 256];
        }
    }
    float loc = at0 + ((tid + 256 < TKv) ? at1 : 0.f);
    red[tid] = loc; __syncthreads();
    for (int s = 128; s > 0; s >>= 1) { if (tid < s) red[tid] += red[tid + s]; __syncthreads(); }
    float S4 = red[0]; __syncthreads();
    out_ant[b * TKv + tid] = at0 / S4;
    if (tid + 256 < TKv) out_ant[b * TKv + tid + 256] = at1 / S4;

    float hvv = g_h[b * 256 + tid], cvv = g_c[b * 256 + tid];
    float xvv = g_x[b * 256 + tid], cdv = g_cd[b * 256 + tid];
    float part = cdv * Wpg[tid]        + cg  * Wpg[256 + tid]
               + cg2 * Wpg[512 + tid]  + hvv * Wpg[768 + tid]
               + cvv * Wpg[1024 + tid] + xvv * Wpg[1280 + tid];
    red[tid] = part; __syncthreads();
    for (int s = 128; s > 0; s >>= 1) { if (tid < s) red[tid] += red[tid + s]; __syncthreads(); }
    float pg = sigm(red[0] + bpg[0]);
    __syncthreads();
    if (tid == 0) { g_pg[b] = pg; out_pgen[b] = pg; }

    cat[tid] = hvv; cat[256 + tid] = cdv; cat[512 + tid] = cg; cat[768 + tid] = cg2;
    __syncthreads();
    float o = b1[tid];
    const float* w1c = W1 + tid;
    #pragma unroll 4
    for (int k = 0; k < 1024; k++) o += cat[k] * w1c[k * 256];
    g_o1[b * 256 + tid] = o;
}

// ---------------------------------------------------------------------------
// K7 (MFMA): logits = out1[128,256] @ W2[256,50000] + b2 -> g_logits (f32).
// W2t bf16 [VPAD][256]. grid (392): each block does all 128 rows x 128 cols.
// Per wave: 2 M-tiles (32 rows) x 8 N-tiles; acc = 64 VGPRs.
// ---------------------------------------------------------------------------
__global__ __launch_bounds__(256) void k_logits(const float* __restrict__ b2)
{
    const int v0 = blockIdx.x * 128;
    const int tid = threadIdx.x;
    const int lane = tid & 63, wave = tid >> 6;
    const int nlow = lane & 15, quad = lane >> 4;

    const float* a0p = g_o1 + (wave * 32 + nlow) * 256 + quad * 8;
    const float* a1p = a0p + 16 * 256;
    const u16* bbase = g_W2t + (size_t)(v0 + nlow) * 256 + quad * 8;

    const f32x4 zf = {0.f, 0.f, 0.f, 0.f};
    f32x4 acc0[8], acc1[8];
    #pragma unroll
    for (int i = 0; i < 8; i++) { acc0[i] = zf; acc1[i] = zf; }

    for (int k0 = 0; k0 < 256; k0 += 32) {
        bf16x8 a0 = cvt8(a0p + k0);
        bf16x8 a1 = cvt8(a1p + k0);
        #pragma unroll
        for (int nt = 0; nt < 8; nt++) {
            bf16x8 bf = *(const bf16x8*)(bbase + (size_t)nt * 4096 + k0);
            acc0[nt] = __builtin_amdgcn_mfma_f32_16x16x32_bf16(a0, bf, acc0[nt], 0, 0, 0);
            acc1[nt] = __builtin_amdgcn_mfma_f32_16x16x32_bf16(a1, bf, acc1[nt], 0, 0, 0);
        }
    }

    #pragma unroll
    for (int nt = 0; nt < 8; nt++) {
        int v = v0 + nt * 16 + nlow;
        if (v < Vv) {
            float bb = b2[v];
            #pragma unroll
            for (int r = 0; r < 4; r++) {
                int row0 = wave * 32 + quad * 4 + r;
                g_logits[(size_t)row0 * Vv + v]        = acc0[nt][r] + bb;
                g_logits[(size_t)(row0 + 16) * Vv + v] = acc1[nt][r] + bb;
            }
        }
    }
}

// ---------------------------------------------------------------------------
// K8: fused per-row softmax over V (f32 g_logits -> f32 out, scaled by
// p_gen) + row-local pointer scatter (1-pg)*a[b,t] at voc_d[b,t].
// ---------------------------------------------------------------------------
__global__ __launch_bounds__(256) void k_vsoft(
    float* __restrict__ outF, const int* __restrict__ vocd)
{
    const int b = blockIdx.x, tid = threadIdx.x;
    __shared__ float rm[256], rs[256];
    const float* Lb = g_logits + (size_t)b * Vv;
    float* Ob = outF + (size_t)b * Vv;

    float m = -1e30f, s = 0.f;
    for (int v = tid; v < Vv; v += 256) {
        float x = Lb[v];
        if (x > m) { s = s * expf(m - x) + 1.f; m = x; }
        else       { s += expf(x - m); }
    }
    rm[tid] = m; rs[tid] = s; __syncthreads();
    for (int off = 128; off > 0; off >>= 1) {
        if (tid < off) {
            float m1 = rm[tid], m2 = rm[tid + off], s1 = rs[tid], s2 = rs[tid + off];
            float M = fmaxf(m1, m2);
            rs[tid] = s1 * expf(m1 - M) + s2 * expf(m2 - M);
            rm[tid] = M;
        }
        __syncthreads();
    }
    const float M = rm[0];
    const float pg = g_pg[b];
    const float inv = pg / rs[0];
    for (int v = tid; v < Vv; v += 256) Ob[v] = expf(Lb[v] - M) * inv;

    __threadfence();
    __syncthreads();

    const float omp = 1.f - pg;
    for (int t = tid; t < TKv; t += 256)
        atomicAdd(Ob + vocd[b * TKv + t], omp * g_a[b * TKv + t]);
}

// ---------------------------------------------------------------------------

extern "C" void kernel_launch(void* const* d_in, const int* in_sizes, int n_in,
                              void* d_out, int out_size, void* d_ws, size_t ws_size,
                              hipStream_t stream)
{
    (void)in_sizes; (void)n_in; (void)out_size; (void)d_ws; (void)ws_size;

    const int*   y      = (const int*)d_in[0];
    const float* h_prev = (const float*)d_in[1];
    const float* c_prev = (const float*)d_in[2];
    const float* enc    = (const float*)d_in[3];
    const float* encn   = (const float*)d_in[4];
    const float* mask   = (const float*)d_in[5];
    const float* maskn  = (const float*)d_in[6];
    const float* ctd    = (const float*)d_in[7];
    const float* ctg    = (const float*)d_in[8];
    const float* ctg2   = (const float*)d_in[9];
    const float* cov    = (const float*)d_in[10];
    const float* flow   = (const float*)d_in[11];
    const float* n2t    = (const float*)d_in[12];
    const float* graph  = (const float*)d_in[13];
    const int*   vocd   = (const int*)d_in[14];
    // d_in[15] = step (unused)
    const float* emb    = (const float*)d_in[16];
    const float* Wx     = (const float*)d_in[17];
    const float* bx     = (const float*)d_in[18];
    const float* Wi     = (const float*)d_in[19];
    const float* Wh     = (const float*)d_in[20];
    const float* bi     = (const float*)d_in[21];
    const float* bh     = (const float*)d_in[22];
    const float* Whd    = (const float*)d_in[23];
    const float* Wsd    = (const float*)d_in[24];
    const float* wcdw   = (const float*)d_in[25];
    const float* vd     = (const float*)d_in[26];
    const float* bd     = (const float*)d_in[27];
    const float* Wn     = (const float*)d_in[28];
    const float* Wsf    = (const float*)d_in[29];
    const float* vf     = (const float*)d_in[30];
    const float* bfv    = (const float*)d_in[31];
    const float* Wpg    = (const float*)d_in[32];
    const float* bpg    = (const float*)d_in[33];
    const float* W1     = (const float*)d_in[34];
    const float* b1     = (const float*)d_in[35];
    const float* W2     = (const float*)d_in[36];
    const float* b2     = (const float*)d_in[37];

    float* o = (float*)d_out;                 // FLOAT32 output
    float* o_final = o;                       // 6,400,000
    float* o_h     = o + 6400000;
    float* o_c     = o + 6432768;
    float* o_cd    = o + 6465536;
    float* o_cg    = o + 6498304;
    float* o_cg2   = o + 6531072;
    float* o_a     = o + 6563840;
    float* o_ant   = o + 6615040;
    float* o_pg    = o + 6666240;
    float* o_cov   = o + 6666368;
    float* o_fl    = o + 6717568;

    float* g_e_p;   hipGetSymbolAddress((void**)&g_e_p,   HIP_SYMBOL(g_e));
    float* g_en_p;  hipGetSymbolAddress((void**)&g_en_p,  HIP_SYMBOL(g_en));
    float* g_sd_p;  hipGetSymbolAddress((void**)&g_sd_p,  HIP_SYMBOL(g_sd));
    float* g_sf_p;  hipGetSymbolAddress((void**)&g_sf_p,  HIP_SYMBOL(g_sf));
    u16*   g_Wdt_p; hipGetSymbolAddress((void**)&g_Wdt_p, HIP_SYMBOL(g_Wdt));
    u16*   g_Wnt_p; hipGetSymbolAddress((void**)&g_Wnt_p, HIP_SYMBOL(g_Wnt));
    u16*   g_W2t_p; hipGetSymbolAddress((void**)&g_W2t_p, HIP_SYMBOL(g_W2t));

    // transpose-cast weights to bf16 [n][k]
    k_tc<<<dim3(8, 8), dim3(256), 0, stream>>>(Whd, g_Wdt_p, 256, 256);
    k_tc<<<dim3(8, 8), dim3(256), 0, stream>>>(Wn,  g_Wnt_p, 256, 256);
    k_tc<<<dim3(VPAD / 32, 8), dim3(256), 0, stream>>>(W2, g_W2t_p, 256, Vv);

    k_pre<<<dim3(Bv), dim3(256), 0, stream>>>(
        y, h_prev, c_prev, ctd, ctg, ctg2, emb, Wx, bx, Wi, Wh, bi, bh,
        Wsd, bd, Wsf, bfv, o_h, o_c);

    k_scores<<<dim3(7, Bv), dim3(256), 0, stream>>>(
        enc, TKv, g_Wdt_p, g_sd_p, cov, wcdw, vd, g_e_p);

    k_scores<<<dim3(1, Bv), dim3(256), 0, stream>>>(
        encn, NKv, g_Wnt_p, g_sf_p, nullptr, nullptr, vf, g_en_p);

    k_doc<<<dim3(Bv), dim3(256), 0, stream>>>(
        enc, mask, cov, n2t, o_a, o_cov, o_cd, o_fl);

    k_node<<<dim3(Bv), dim3(256), 0, stream>>>(
        encn, maskn, flow, graph, n2t, Wpg, bpg, W1, b1,
        o_cg, o_cg2, o_ant, o_pg);

    k_logits<<<dim3(VPAD / 128), dim3(256), 0, stream>>>(b2);

    k_vsoft<<<dim3(Bv), dim3(256), 0, stream>>>(o_final, vocd);
}